// Round 9
// baseline (640.252 us; speedup 1.0000x reference)
//
#include <hip/hip_runtime.h>
#include <math.h>

// WaveLM: logits[b,t,v] = sum_{t'<t} g(id[b,t'], v)
// g(u,v) = 2 * sum_{i,j in 1..H} (A_u/i^dec)(A_v/j^dec) * sinc(2*(f_u*i - f_v*j))
// sinc(2d) = sin(2*pi*d)/(2*pi*d), sinc(0)=1
//
// R14: - R13's grid.sync fusion REVERTED (phase2 ran at compute-kernel
//        occupancy and the sync's device fence flushed L2: 255us).
//      - DECOUPLED LOOKBACK single-pass scan instead: each tile block
//        computes, writes local prefix, publishes segment total (agent-
//        scope atomics + release flag), spin-waits on predecessor flags
//        (ticket-ordered -> deadlock-free under any dispatch order), sums
//        predecessor totals from L3, RMWs its OWN 16 rows (L1/L2-hot,
//        overlapped with other blocks' compute). wavelm_addbase (~55us of
//        HBM RMW) eliminated; launches stay 2 (tiny 8KB flag-clear + g2).
//      - Tile math identical to R12; u-side now value-double-buffered
//        ({fu,Au}: 2 SGPRs, loads for token g+1 issue during token g).

typedef float v2f __attribute__((ext_vector_type(2)));

constexpr int cB = 4, cT = 512, cV = 8000, cH = 7;
constexpr int GT = 16;                  // tokens per tile == seglen
constexpr int NSEG = cT / GT;           // 32 segments
constexpr int NXB = (cV / 2 + 255) / 256;   // 16 x-tiles
constexpr int NTILE = NSEG * cB * NXB;  // 2048 tiles, seg-major order

__device__ __forceinline__ v2f pk_add(v2f a, v2f b) {
    v2f d; asm("v_pk_add_f32 %0, %1, %2" : "=v"(d) : "v"(a), "v"(b)); return d;
}
__device__ __forceinline__ v2f pk_mul(v2f a, v2f b) {
    v2f d; asm("v_pk_mul_f32 %0, %1, %2" : "=v"(d) : "v"(a), "v"(b)); return d;
}
__device__ __forceinline__ v2f pk_fma(v2f a, v2f b, v2f c) {
    v2f d; asm("v_pk_fma_f32 %0, %1, %2, %3" : "=v"(d) : "v"(a), "v"(b), "v"(c));
    return d;
}
__device__ __forceinline__ float rfl(float x) {
    return __builtin_bit_cast(float,
        __builtin_amdgcn_readfirstlane(__builtin_bit_cast(int, x)));
}

__device__ __forceinline__ void build_rp(const float* decay_p, float* rp)
{
    const float decay = decay_p[0];
    const float q2 = __builtin_amdgcn_exp2f(-decay);
    const float q3 = __builtin_amdgcn_exp2f(-decay * 1.5849625007f);
    const float q5 = __builtin_amdgcn_exp2f(-decay * 2.3219280949f);
    const float q7 = __builtin_amdgcn_exp2f(-decay * 2.8073549221f);
    rp[0] = 1.f;  rp[1] = q2;      rp[2] = q3;  rp[3] = q2 * q2;
    rp[4] = q5;   rp[5] = q2 * q3; rp[6] = q7;
}

// computes one (bs, xb) tile; writes local prefix (segmode) or raw values;
// returns the tile's segment total for this thread's v-pair.
__device__ __forceinline__ v2f tile_compute(
    const int bs, const int xb, const int* __restrict__ ids,
    const float* __restrict__ freq, const float* __restrict__ amp,
    const float* __restrict__ rp, float* __restrict__ out, const int segmode)
{
    const int bt0 = bs * GT;
    const int vh  = xb * 256 + (int)threadIdx.x;    // v-pair index
    const bool valid = (vh * 2 < cV);
    const int vc = valid ? vh : 0;

    // ---- v-side setup once (tab's math, in-register), amortized over GT ----
    const v2f fv = *(const v2f*)(freq + (size_t)vc * 2);
    const v2f Av = *(const v2f*)(amp  + (size_t)vc * 2);
    v2f nb[cH], sBw[cH], cBw[cH];
    {
        const float xrx = fv.x - rintf(fv.x);
        const float xry = fv.y - rintf(fv.y);
        const float s1x = __builtin_amdgcn_sinf(xrx);
        const float c1x = __builtin_amdgcn_cosf(xrx);
        const float s1y = __builtin_amdgcn_sinf(xry);
        const float c1y = __builtin_amdgcn_cosf(xry);
        float sx = s1x, cx = c1x, sy = s1y, cy = c1y;
#pragma unroll
        for (int k = 0; k < cH; ++k) {
            if (k) {
                const float spx = sx, cpx = cx, spy = sy, cpy = cy;
                sx = fmaf(spx, c1x,  cpx * s1x);
                cx = fmaf(cpx, c1x, -(spx * s1x));
                sy = fmaf(spy, c1y,  cpy * s1y);
                cy = fmaf(cpy, c1y, -(spy * s1y));
            }
            const float wx = Av.x * rp[k];          // tab plane 14+k
            const float wy = Av.y * rp[k];
            const float wsx = wx * 0.15915494309189535f;  // w/(2pi)
            const float wsy = wy * 0.15915494309189535f;
            sBw[k].x = sx * wsx;  sBw[k].y = sy * wsy;
            cBw[k].x = cx * wsx;  cBw[k].y = cy * wsy;
            nb[k].x = -(fv.x * (float)(k + 1));     // tab plane 21+k, negated
            nb[k].y = -(fv.y * (float)(k + 1));
        }
    }

    v2f acc;  acc.x = 0.f;  acc.y = 0.f;            // running segment prefix

    int idc = ids[bt0];                             // current token id (SGPR)
    float fu = freq[idc], Au = amp[idc];            // value double-buffer
    for (int g = 0; g < GT; ++g) {
        // prefetch NEXT token's id AND values (2 SGPRs); loads complete
        // under this token's ~1400-cycle compute
        const int idn = (g + 1 < GT) ? ids[bt0 + g + 1] : idc;
        const float fn = freq[idn];
        const float An = amp[idn];

        const float xru = fu - rintf(fu);
        const float s1u = rfl(__builtin_amdgcn_sinf(xru));
        const float c1u = rfl(__builtin_amdgcn_cosf(xru));

        float accx = 0.f, accy = 0.f;
        float su = s1u, cu = c1u;                   // sin/cos(2pi f (i+1))
#pragma unroll
        for (int i = 0; i < cH; ++i) {
            if (i) { const float sp = su, cp = cu;
                     su = fmaf(sp, c1u,  cp * s1u);
                     cu = fmaf(cp, c1u, -(sp * s1u)); }
            const float au = fu * (float)(i + 1);   // same op as tab plane 21
            v2f ai;  ai.x = au;  ai.y = au;
            v2f d[cH], p[cH];
#pragma unroll
            for (int j = 0; j < cH; ++j) d[j] = pk_add(ai, nb[j]);
            p[0] = d[0];
#pragma unroll
            for (int j = 1; j < cH; ++j) p[j] = pk_mul(p[j-1], d[j]);
            const float ptot = p[6].x * p[6].y;
            const float rt = __builtin_amdgcn_rcpf(ptot);
            v2f r;  r.x = rt * p[6].y;  r.y = rt * p[6].x;   // 1/p6 per comp
            v2f accS = (v2f)0.f, accC = (v2f)0.f;
#pragma unroll
            for (int j = cH - 1; j >= 1; --j) {
                const v2f inv = pk_mul(r, p[j-1]);
                accS = pk_fma(cBw[j], inv, accS);
                accC = pk_fma(sBw[j], inv, accC);
                r = pk_mul(r, d[j]);
            }
            accS = pk_fma(cBw[0], r, accS);
            accC = pk_fma(sBw[0], r, accC);
            // sum_j sn_j*inv_j = su*accS - cu*accC  (per component)
            const float tx = fmaf(su, accS.x, -(cu * accC.x));
            const float ty = fmaf(su, accS.y, -(cu * accC.y));
            accx = fmaf(rp[i], tx, accx);
            accy = fmaf(rp[i], ty, accy);
        }

        // rare guarded path. Any d==0 / underflow-to-0 / overflow produces
        // inf or NaN in accx/accy (rcp(0)=inf; inf*0=NaN; finite overflow of
        // intermediates impossible: |p6| <= ~1e16). NaN fails |x|<1e30 too.
        if (!(fabsf(accx) < 1e30f) || !(fabsf(accy) < 1e30f)) {
            accx = 0.f;  accy = 0.f;
            float s2 = s1u, c2 = c1u;
#pragma unroll
            for (int i = 0; i < cH; ++i) {
                if (i) { const float sp = s2, cp = c2;
                         s2 = fmaf(sp, c1u,  cp * s1u);
                         c2 = fmaf(cp, c1u, -(sp * s1u)); }
                const float au = fu * (float)(i + 1);
                float ax = 0.f, ay = 0.f;
#pragma unroll
                for (int j = 0; j < cH; ++j) {
                    const float wxx = Av.x * rp[j];     // tab plane 14+j
                    const float wyy = Av.y * rp[j];
                    const float dx = au + nb[j].x;
                    const float dy = au + nb[j].y;
                    const float snx = fmaf(s2, cBw[j].x, -(c2 * sBw[j].x));
                    const float sny = fmaf(s2, cBw[j].y, -(c2 * sBw[j].y));
                    float qx = snx * __builtin_amdgcn_rcpf(dx);
                    float qy = sny * __builtin_amdgcn_rcpf(dy);
                    qx = (dx == 0.f) ? wxx : qx;
                    qy = (dy == 0.f) ? wyy : qy;
                    ax += qx;  ay += qy;
                }
                accx = fmaf(rp[i], ax, accx);
                accy = fmaf(rp[i], ay, accy);
            }
        }

        if (valid) {
            const float A2 = 2.f * Au;
            v2f res;  res.x = A2 * accx;  res.y = A2 * accy;
            const size_t o = (size_t)(bt0 + g) * cV + (size_t)vh * 2;
            v2f wv;  wv.x = segmode ? acc.x : res.x;
                     wv.y = segmode ? acc.y : res.y;
            *(v2f*)(out + o) = wv;
            acc = pk_add(acc, res);
        }

        idc = idn;  fu = fn;  Au = An;
    }
    return acc;
}

// ---- flag/ticket clear (8.2 KB) -----------------------------------------

__global__ __launch_bounds__(256) void wavelm_clear(int* __restrict__ flags)
{
    const int i = blockIdx.x * 256 + threadIdx.x;
    if (i < NTILE + 1) flags[i] = 0;    // [0] = ticket counter, [1..] flags
}

// ---- single-pass compute + decoupled-lookback scan ----------------------

__global__ __launch_bounds__(256) void wavelm_g2(
    const int* __restrict__ ids, const float* __restrict__ freq,
    const float* __restrict__ amp, const float* __restrict__ decay_p,
    float* __restrict__ out, float* __restrict__ segsum,
    int* __restrict__ flags)
{
    // ticket: tiles claimed in block-START order -> a spinner only ever
    // waits on earlier-started blocks (seg-major order) -> no deadlock
    // regardless of dispatch order.
    __shared__ int s_t;
    if (threadIdx.x == 0)
        s_t = __hip_atomic_fetch_add(&flags[0], 1, __ATOMIC_RELAXED,
                                     __HIP_MEMORY_SCOPE_AGENT);
    __syncthreads();
    const int t   = s_t;
    const int xb  = t & (NXB - 1);
    const int b   = (t >> 4) & (cB - 1);
    const int seg = t >> 6;                     // t / (NXB*cB)
    const int bs  = b * NSEG + seg;

    float rp[cH];
    build_rp(decay_p, rp);

    const int vh  = xb * 256 + (int)threadIdx.x;
    const bool valid = (vh * 2 < cV);

    v2f acc;  acc.x = 0.f;  acc.y = 0.f;
    // wave-uniform skip for fully-invalid waves (no syncthreads inside)
    if ((xb * 256 + (int)(threadIdx.x & 192u)) * 2 < cV)
        acc = tile_compute(bs, xb, ids, freq, amp, rp, out, 1);

    // publish segment total at agent scope, then release flag
    if (valid) {
        const size_t si = (size_t)bs * cV + (size_t)vh * 2;
        __hip_atomic_store(&segsum[si],     acc.x, __ATOMIC_RELAXED,
                           __HIP_MEMORY_SCOPE_AGENT);
        __hip_atomic_store(&segsum[si + 1], acc.y, __ATOMIC_RELAXED,
                           __HIP_MEMORY_SCOPE_AGENT);
    }
    __threadfence();
    __syncthreads();
    if (threadIdx.x == 0)
        __hip_atomic_store(&flags[1 + t], 1, __ATOMIC_RELEASE,
                           __HIP_MEMORY_SCOPE_AGENT);

    if (seg == 0) return;                       // rows already final

    // lookback: wait for the seg predecessors of this (b, xb) column
    if (threadIdx.x == 0) {
        for (int s = 0; s < seg; ++s) {
            const int pt = (s * cB + b) * NXB + xb;
            while (__hip_atomic_load(&flags[1 + pt], __ATOMIC_ACQUIRE,
                                     __HIP_MEMORY_SCOPE_AGENT) == 0)
                __builtin_amdgcn_s_sleep(8);
        }
    }
    __syncthreads();

    if (!valid) return;

    float bx = 0.f, by = 0.f;
    for (int s = 0; s < seg; ++s) {
        const size_t si = ((size_t)(b * NSEG + s)) * cV + (size_t)vh * 2;
        bx += __hip_atomic_load(&segsum[si],     __ATOMIC_RELAXED,
                                __HIP_MEMORY_SCOPE_AGENT);
        by += __hip_atomic_load(&segsum[si + 1], __ATOMIC_RELAXED,
                                __HIP_MEMORY_SCOPE_AGENT);
    }

    // RMW our OWN 16 just-written rows (L1/L2-hot, overlapped w/ compute)
    const size_t o0 = (size_t)bs * GT * cV + (size_t)vh * 2;
    for (int g = 0; g < GT; ++g) {
        v2f x = *(v2f*)(out + o0 + (size_t)g * cV);
        x.x += bx;  x.y += by;
        *(v2f*)(out + o0 + (size_t)g * cV) = x;
    }
}

// ---- fallback path (ws too small): raw values + full-chain scan ---------

__global__ __launch_bounds__(256) void wavelm_g(
    const int* __restrict__ ids, const float* __restrict__ freq,
    const float* __restrict__ amp, const float* __restrict__ decay_p,
    float* __restrict__ out)
{
    const int bs = blockIdx.y, xb = blockIdx.x;
    if ((xb * 256 + (int)(threadIdx.x & 192u)) * 2 >= cV) return;
    float rp[cH];
    build_rp(decay_p, rp);
    (void)tile_compute(bs, xb, ids, freq, amp, rp, out, 0);
}

__global__ __launch_bounds__(256) void wavelm_scan(float* __restrict__ out)
{
    const int g = blockIdx.x * blockDim.x + threadIdx.x;
    if (g >= cB * cV) return;
    const int b = g / cV;
    const int v = g - b * cV;
    float* p = out + (size_t)b * cT * cV + v;
    float acc = 0.f;
#pragma unroll 8
    for (int t = 0; t < cT; ++t) {
        const float c = p[(size_t)t * cV];
        p[(size_t)t * cV] = acc;
        acc += c;
    }
}

extern "C" void kernel_launch(void* const* d_in, const int* in_sizes, int n_in,
                              void* d_out, int out_size, void* d_ws, size_t ws_size,
                              hipStream_t stream)
{
    const int*   ids  = (const int*)d_in[0];
    const float* freq = (const float*)d_in[1];
    const float* amp  = (const float*)d_in[2];
    const float* dec  = (const float*)d_in[3];
    float* out = (float*)d_out;

    // ws layout: segsum (4 MB) | flags (NTILE+1 ints)
    float* segsum = (float*)d_ws;
    const size_t seg_f = (size_t)cB * NSEG * cV;         // floats
    int* flags = (int*)(segsum + seg_f);
    const size_t need = seg_f * sizeof(float) + (NTILE + 1) * sizeof(int);

    if (need <= ws_size) {
        wavelm_clear<<<(NTILE + 256) / 256, dim3(256), 0, stream>>>(flags);
        wavelm_g2<<<dim3(NTILE), dim3(256), 0, stream>>>(
            ids, freq, amp, dec, out, segsum, flags);
    } else {
        dim3 grid(NXB, cB * NSEG);                       // 16 x 128
        wavelm_g<<<grid, dim3(256), 0, stream>>>(ids, freq, amp, dec, out);
        const int nchains = cB * cV;
        wavelm_scan<<<(nchains + 255) / 256, dim3(256), 0, stream>>>(out);
    }
}

// Round 10
// 202.932 us; speedup vs baseline: 3.1550x; 3.1550x over previous
//
#include <hip/hip_runtime.h>
#include <math.h>

// WaveLM: logits[b,t,v] = sum_{t'<t} g(id[b,t'], v)
// g(u,v) = 2 * sum_{i,j in 1..H} (A_u/i^dec)(A_v/j^dec) * sinc(2*(f_u*i - f_v*j))
// sinc(2d) = sin(2*pi*d)/(2*pi*d), sinc(0)=1
//
// R15: - R13 (grid.sync fusion) and R14 (decoupled lookback) both REVERTED:
//        on MI355X agent-scope acquire/release = per-XCD L2 inv/writeback
//        (L2s not cross-coherent; coherence point is L3), so global-barrier
//        and message-passing scans thrash L2 (R13 255us, R14 600us).
//        R12's two-kernel structure restored (best: 203.4us).
//      - KEPT from R14: u-side VALUE double-buffer ({fu,Au} of token g+1
//        prefetched at top of token g; 2 SGPRs). Removes the per-token
//        serial head (s_load 200-900cyc -> sin/cos -> i=0) that R12 paid;
//        load latency now hides under the previous token's ~1370-cyc
//        compute. (R6's failure was buffering 28 VALUES; 2 is free.)
//      - Everything else identical to R12: packed 2-v/lane, in-register
//        table math, finite-check guard, GT=16 fused segment scan,
//        fused-lookback addbase, wave-uniform early exits.

typedef float v2f __attribute__((ext_vector_type(2)));
typedef float v4f __attribute__((ext_vector_type(4)));

constexpr int cB = 4, cT = 512, cV = 8000, cH = 7;
constexpr int GT = 16;                // tokens per wavelm_g block == seglen
constexpr int NSEG = cT / GT;         // 32 segments
constexpr int NXB = (cV / 2 + 255) / 256;   // 16 x-tiles

__device__ __forceinline__ v2f pk_add(v2f a, v2f b) {
    v2f d; asm("v_pk_add_f32 %0, %1, %2" : "=v"(d) : "v"(a), "v"(b)); return d;
}
__device__ __forceinline__ v2f pk_mul(v2f a, v2f b) {
    v2f d; asm("v_pk_mul_f32 %0, %1, %2" : "=v"(d) : "v"(a), "v"(b)); return d;
}
__device__ __forceinline__ v2f pk_fma(v2f a, v2f b, v2f c) {
    v2f d; asm("v_pk_fma_f32 %0, %1, %2, %3" : "=v"(d) : "v"(a), "v"(b), "v"(c));
    return d;
}
__device__ __forceinline__ float rfl(float x) {
    return __builtin_bit_cast(float,
        __builtin_amdgcn_readfirstlane(__builtin_bit_cast(int, x)));
}

__global__ __launch_bounds__(256) void wavelm_g(
    const int* __restrict__ ids, const float* __restrict__ freq,
    const float* __restrict__ amp, const float* __restrict__ decay_p,
    float* __restrict__ out, float* __restrict__ segsum, const int segmode)
{
    const int bs  = blockIdx.y;                     // (b, seg) flattened
    const int bt0 = bs * GT;
    // wave-uniform early exit for fully-invalid waves
    if ((blockIdx.x * 256 + (int)(threadIdx.x & 192u)) * 2 >= cV) return;
    const int vh  = blockIdx.x * 256 + threadIdx.x; // v-pair index
    const bool valid = (vh * 2 < cV);
    const int vc = valid ? vh : 0;

    // rp[k] = (k+1)^-decay, uniform; identical ops to the old wavelm_tab
    const float decay = decay_p[0];
    const float q2 = __builtin_amdgcn_exp2f(-decay);
    const float q3 = __builtin_amdgcn_exp2f(-decay * 1.5849625007f);
    const float q5 = __builtin_amdgcn_exp2f(-decay * 2.3219280949f);
    const float q7 = __builtin_amdgcn_exp2f(-decay * 2.8073549221f);
    const float rp[7] = {1.f, q2, q3, q2*q2, q5, q2*q3, q7};

    // ---- v-side setup once (tab's math, in-register), amortized over GT ----
    const v2f fv = *(const v2f*)(freq + (size_t)vc * 2);
    const v2f Av = *(const v2f*)(amp  + (size_t)vc * 2);
    v2f nb[cH], sBw[cH], cBw[cH];
    {
        const float xrx = fv.x - rintf(fv.x);
        const float xry = fv.y - rintf(fv.y);
        const float s1x = __builtin_amdgcn_sinf(xrx);
        const float c1x = __builtin_amdgcn_cosf(xrx);
        const float s1y = __builtin_amdgcn_sinf(xry);
        const float c1y = __builtin_amdgcn_cosf(xry);
        float sx = s1x, cx = c1x, sy = s1y, cy = c1y;
#pragma unroll
        for (int k = 0; k < cH; ++k) {
            if (k) {
                const float spx = sx, cpx = cx, spy = sy, cpy = cy;
                sx = fmaf(spx, c1x,  cpx * s1x);
                cx = fmaf(cpx, c1x, -(spx * s1x));
                sy = fmaf(spy, c1y,  cpy * s1y);
                cy = fmaf(cpy, c1y, -(spy * s1y));
            }
            const float wx = Av.x * rp[k];          // tab plane 14+k
            const float wy = Av.y * rp[k];
            const float wsx = wx * 0.15915494309189535f;  // w/(2pi)
            const float wsy = wy * 0.15915494309189535f;
            sBw[k].x = sx * wsx;  sBw[k].y = sy * wsy;
            cBw[k].x = cx * wsx;  cBw[k].y = cy * wsy;
            nb[k].x = -(fv.x * (float)(k + 1));     // tab plane 21+k, negated
            nb[k].y = -(fv.y * (float)(k + 1));
        }
    }

    v2f acc;  acc.x = 0.f;  acc.y = 0.f;            // running segment prefix

    int idc = ids[bt0];                             // current token id (SGPR)
    float fu = freq[idc], Au = amp[idc];            // value double-buffer
    for (int g = 0; g < GT; ++g) {
        // prefetch NEXT token's id AND values (2 SGPRs); the loads retire
        // under THIS token's ~1370-cycle compute
        const int idn = (g + 1 < GT) ? ids[bt0 + g + 1] : idc;
        const float fn = freq[idn];
        const float An = amp[idn];

        const float xru = fu - rintf(fu);
        const float s1u = rfl(__builtin_amdgcn_sinf(xru));
        const float c1u = rfl(__builtin_amdgcn_cosf(xru));

        float accx = 0.f, accy = 0.f;
        float su = s1u, cu = c1u;                   // sin/cos(2pi f (i+1))
#pragma unroll
        for (int i = 0; i < cH; ++i) {
            if (i) { const float sp = su, cp = cu;
                     su = fmaf(sp, c1u,  cp * s1u);
                     cu = fmaf(cp, c1u, -(sp * s1u)); }
            const float au = fu * (float)(i + 1);   // same op as tab plane 21
            v2f ai;  ai.x = au;  ai.y = au;
            v2f d[cH], p[cH];
#pragma unroll
            for (int j = 0; j < cH; ++j) d[j] = pk_add(ai, nb[j]);
            p[0] = d[0];
#pragma unroll
            for (int j = 1; j < cH; ++j) p[j] = pk_mul(p[j-1], d[j]);
            const float ptot = p[6].x * p[6].y;
            const float rt = __builtin_amdgcn_rcpf(ptot);
            v2f r;  r.x = rt * p[6].y;  r.y = rt * p[6].x;   // 1/p6 per comp
            v2f accS = (v2f)0.f, accC = (v2f)0.f;
#pragma unroll
            for (int j = cH - 1; j >= 1; --j) {
                const v2f inv = pk_mul(r, p[j-1]);
                accS = pk_fma(cBw[j], inv, accS);
                accC = pk_fma(sBw[j], inv, accC);
                r = pk_mul(r, d[j]);
            }
            accS = pk_fma(cBw[0], r, accS);
            accC = pk_fma(sBw[0], r, accC);
            // sum_j sn_j*inv_j = su*accS - cu*accC  (per component)
            const float tx = fmaf(su, accS.x, -(cu * accC.x));
            const float ty = fmaf(su, accS.y, -(cu * accC.y));
            accx = fmaf(rp[i], tx, accx);
            accy = fmaf(rp[i], ty, accy);
        }

        // rare guarded path. Any d==0 / underflow-to-0 / overflow produces
        // inf or NaN in accx/accy (rcp(0)=inf; inf*0=NaN; finite overflow of
        // intermediates impossible: |p6| <= ~1e16). NaN fails |x|<1e30 too.
        if (!(fabsf(accx) < 1e30f) || !(fabsf(accy) < 1e30f)) {
            accx = 0.f;  accy = 0.f;
            float s2 = s1u, c2 = c1u;
#pragma unroll
            for (int i = 0; i < cH; ++i) {
                if (i) { const float sp = s2, cp = c2;
                         s2 = fmaf(sp, c1u,  cp * s1u);
                         c2 = fmaf(cp, c1u, -(sp * s1u)); }
                const float au = fu * (float)(i + 1);
                float ax = 0.f, ay = 0.f;
#pragma unroll
                for (int j = 0; j < cH; ++j) {
                    const float wxx = Av.x * rp[j];     // tab plane 14+j
                    const float wyy = Av.y * rp[j];
                    const float dx = au + nb[j].x;
                    const float dy = au + nb[j].y;
                    const float snx = fmaf(s2, cBw[j].x, -(c2 * sBw[j].x));
                    const float sny = fmaf(s2, cBw[j].y, -(c2 * sBw[j].y));
                    float qx = snx * __builtin_amdgcn_rcpf(dx);
                    float qy = sny * __builtin_amdgcn_rcpf(dy);
                    qx = (dx == 0.f) ? wxx : qx;
                    qy = (dy == 0.f) ? wyy : qy;
                    ax += qx;  ay += qy;
                }
                accx = fmaf(rp[i], ax, accx);
                accy = fmaf(rp[i], ay, accy);
            }
        }

        if (valid) {
            const float A2 = 2.f * Au;
            v2f res;  res.x = A2 * accx;  res.y = A2 * accy;
            const size_t o = (size_t)(bt0 + g) * cV + (size_t)vh * 2;
            // segmode: write shifted local prefix; else raw value
            v2f wv;  wv.x = segmode ? acc.x : res.x;
                     wv.y = segmode ? acc.y : res.y;
            *(v2f*)(out + o) = wv;
            acc = pk_add(acc, res);
        }

        idc = idn;  fu = fn;  Au = An;
    }

    if (valid && segmode)
        *(v2f*)(segsum + (size_t)bs * cV + (size_t)vh * 2) = acc;
}

// out[b,t,v] += sum_{sp<seg} segsum[b,sp,v]; lookback fused; segsum is 4MB
// -> L2/L3-resident for the re-reads; out re-read mostly L3-hits (just
// written by wavelm_g).
__global__ __launch_bounds__(256) void wavelm_addbase(
    float* __restrict__ out, const float* __restrict__ segsum)
{
    const int btq = blockIdx.y;          // b*(cT/8) + t-octet
    const int b  = btq >> 6;             // cT/8 = 64
    const int t0 = (btq & 63) * 8;
    const int seg = t0 / GT;
    if (seg == 0) return;                // base is zero: out already final
    const int v4 = blockIdx.x * 256 + threadIdx.x;
    if (v4 >= cV / 4) return;

    const float* sp = segsum + (size_t)b * NSEG * cV + (size_t)v4 * 4;
    v4f base;  base.x = 0.f;  base.y = 0.f;  base.z = 0.f;  base.w = 0.f;
    for (int s = 0; s < seg; ++s) {
        const v4f x = *(const v4f*)(sp + (size_t)s * cV);
        base.x += x.x;  base.y += x.y;  base.z += x.z;  base.w += x.w;
    }

    float* p = out + ((size_t)b * cT + t0) * cV + (size_t)v4 * 4;
#pragma unroll
    for (int k = 0; k < 8; ++k) {
        v4f x = *(v4f*)(p + (size_t)k * cV);
        x.x += base.x;  x.y += base.y;  x.z += base.z;  x.w += base.w;
        *(v4f*)(p + (size_t)k * cV) = x;
    }
}

// fallback full-chain scan (ws too small for segsum)
__global__ __launch_bounds__(256) void wavelm_scan(float* __restrict__ out)
{
    const int g = blockIdx.x * blockDim.x + threadIdx.x;
    if (g >= cB * cV) return;
    const int b = g / cV;
    const int v = g - b * cV;
    float* p = out + (size_t)b * cT * cV + v;
    float acc = 0.f;
#pragma unroll 8
    for (int t = 0; t < cT; ++t) {
        const float c = p[(size_t)t * cV];
        p[(size_t)t * cV] = acc;
        acc += c;
    }
}

extern "C" void kernel_launch(void* const* d_in, const int* in_sizes, int n_in,
                              void* d_out, int out_size, void* d_ws, size_t ws_size,
                              hipStream_t stream)
{
    const int*   ids  = (const int*)d_in[0];
    const float* freq = (const float*)d_in[1];
    const float* amp  = (const float*)d_in[2];
    const float* dec  = (const float*)d_in[3];
    float* out = (float*)d_out;
    float* segsum = (float*)d_ws;                        // 4*32*8000*4 = 4 MB

    const size_t seg_b = (size_t)cB * NSEG * cV * sizeof(float);
    const int segmode = (seg_b <= ws_size) ? 1 : 0;

    dim3 grid(NXB, cB * NSEG);                           // 16 x 128
    wavelm_g<<<grid, dim3(256), 0, stream>>>(ids, freq, amp, dec,
                                             out, segsum, segmode);

    if (segmode) {
        dim3 ab((cV / 4 + 255) / 256, cB * (cT / 8));    // 8 x 256
        wavelm_addbase<<<ab, dim3(256), 0, stream>>>(out, segsum);
    } else {
        const int nchains = cB * cV;
        wavelm_scan<<<(nchains + 255) / 256, dim3(256), 0, stream>>>(out);
    }
}